// Round 1
// baseline (3371.188 us; speedup 1.0000x reference)
//
#include <hip/hip_runtime.h>
#include <cstdint>
#include <cstddef>

#define B_   2
#define CD_  512      // DIM
#define L_   4096     // H*W
#define DI_  1024     // D_INNER
#define NT_  (B_*L_)  // tokens = 8192

typedef unsigned short u16;
typedef __attribute__((ext_vector_type(8))) short bf16x8;
typedef __attribute__((ext_vector_type(4))) float f32x4;

__device__ __forceinline__ float clampf(float x){ return fminf(10.f, fmaxf(-10.f, x)); }

__device__ __forceinline__ u16 f2b(float f){
  union { float f; unsigned u; } v; v.f = f;
  unsigned u = v.u + 0x7FFFu + ((v.u >> 16) & 1u);   // RNE to bf16
  return (u16)(u >> 16);
}

// ---------------- transpose + clamp: in (B,R,Cc) -> out (B,Cc,R) ----------------
__global__ __launch_bounds__(256) void k_transpose(const float* __restrict__ in,
                                                   float* __restrict__ out,
                                                   int R, int Cc)
{
  __shared__ float tile[32][33];
  int b = blockIdx.z;
  int c0 = blockIdx.x * 32, r0 = blockIdx.y * 32;
  #pragma unroll
  for (int i = 0; i < 32; i += 8) {
    int r = r0 + threadIdx.y + i, c = c0 + threadIdx.x;
    tile[threadIdx.y + i][threadIdx.x] = in[((size_t)b * R + r) * Cc + c];
  }
  __syncthreads();
  #pragma unroll
  for (int i = 0; i < 32; i += 8) {
    int c = c0 + threadIdx.y + i, r = r0 + threadIdx.x;
    out[((size_t)b * Cc + c) * R + r] = clampf(tile[threadIdx.x][threadIdx.y + i]);
  }
}

// ---------------- LN1: per-token layernorm over 512, writes bf16 ----------------
__global__ __launch_bounds__(64) void k_ln1(const float* __restrict__ xt,
                                            const float* __restrict__ w,
                                            const float* __restrict__ bias,
                                            u16* __restrict__ out)
{
  int t = blockIdx.x, lane = threadIdx.x;
  const float4* row = (const float4*)(xt + (size_t)t * CD_);
  float4 a = row[lane], b = row[lane + 64];
  float s = a.x + a.y + a.z + a.w + b.x + b.y + b.z + b.w;
  float q = a.x*a.x + a.y*a.y + a.z*a.z + a.w*a.w
          + b.x*b.x + b.y*b.y + b.z*b.z + b.w*b.w;
  #pragma unroll
  for (int off = 32; off; off >>= 1) { s += __shfl_xor(s, off, 64); q += __shfl_xor(q, off, 64); }
  float mu = s * (1.f / CD_);
  float rs = rsqrtf(q * (1.f / CD_) - mu * mu + 1e-5f);
  const float4* wv = (const float4*)w;  const float4* bv = (const float4*)bias;
  float4 w0 = wv[lane], w1 = wv[lane + 64], b0 = bv[lane], b1 = bv[lane + 64];
  u16* orow = out + (size_t)t * CD_;
  ushort4 o0, o1;
  o0.x = f2b(clampf((a.x - mu) * rs * w0.x + b0.x));
  o0.y = f2b(clampf((a.y - mu) * rs * w0.y + b0.y));
  o0.z = f2b(clampf((a.z - mu) * rs * w0.z + b0.z));
  o0.w = f2b(clampf((a.w - mu) * rs * w0.w + b0.w));
  o1.x = f2b(clampf((b.x - mu) * rs * w1.x + b1.x));
  o1.y = f2b(clampf((b.y - mu) * rs * w1.y + b1.y));
  o1.z = f2b(clampf((b.z - mu) * rs * w1.z + b1.z));
  o1.w = f2b(clampf((b.w - mu) * rs * w1.w + b1.w));
  ((ushort4*)orow)[lane] = o0;
  ((ushort4*)orow)[lane + 64] = o1;
}

// ---------------- LN2: clamp -> LN(w=1,b=0) -> clamp, fp32 in-place ----------------
__global__ __launch_bounds__(64) void k_ln2(float* __restrict__ o)
{
  int t = blockIdx.x, lane = threadIdx.x;
  float4* row = (float4*)(o + (size_t)t * CD_);
  float4 a = row[lane], b = row[lane + 64];
  a.x = clampf(a.x); a.y = clampf(a.y); a.z = clampf(a.z); a.w = clampf(a.w);
  b.x = clampf(b.x); b.y = clampf(b.y); b.z = clampf(b.z); b.w = clampf(b.w);
  float s = a.x + a.y + a.z + a.w + b.x + b.y + b.z + b.w;
  float q = a.x*a.x + a.y*a.y + a.z*a.z + a.w*a.w
          + b.x*b.x + b.y*b.y + b.z*b.z + b.w*b.w;
  #pragma unroll
  for (int off = 32; off; off >>= 1) { s += __shfl_xor(s, off, 64); q += __shfl_xor(q, off, 64); }
  float mu = s * (1.f / CD_);
  float rs = rsqrtf(q * (1.f / CD_) - mu * mu + 1e-5f);
  float4 r0, r1;
  r0.x = clampf((a.x - mu) * rs); r0.y = clampf((a.y - mu) * rs);
  r0.z = clampf((a.z - mu) * rs); r0.w = clampf((a.w - mu) * rs);
  r1.x = clampf((b.x - mu) * rs); r1.y = clampf((b.y - mu) * rs);
  r1.z = clampf((b.z - mu) * rs); r1.w = clampf((b.w - mu) * rs);
  row[lane] = r0; row[lane + 64] = r1;
}

// ---------------- fp32 -> bf16 convert ----------------
__global__ __launch_bounds__(256) void k_cvt(const float* __restrict__ in, u16* __restrict__ out, int n)
{
  int i = blockIdx.x * 256 + threadIdx.x;
  if (i < n) out[i] = f2b(in[i]);
}

// ---------------- bf16 MFMA GEMM: C[M,N] = A[M,K] * W[N,K]^T ----------------
// block = 256 threads = 4 waves; block tile M=64 (16 rows/wave), N = NSUB*16.
// Fragment layouts (verified, guide §3): A[m=lane&15][k=(lane>>4)*8+j],
// B[k=(lane>>4)*8+j][n=lane&15]  (from W row n), D: col=lane&15, row=(lane>>4)*4+reg.
template<int NSUB>
__global__ __launch_bounds__(256) void k_gemm(const u16* __restrict__ A, int lda,
                                              const u16* __restrict__ W, int ldb,
                                              float* __restrict__ C, int ldc,
                                              int K)
{
  int lane = threadIdx.x & 63;
  int wv   = threadIdx.x >> 6;
  int m0 = blockIdx.y * 64 + wv * 16;
  int n0 = blockIdx.x * (NSUB * 16);
  int r15 = lane & 15;
  int kq  = (lane >> 4) * 8;
  const u16* ap = A + (size_t)(m0 + r15) * lda + kq;
  const u16* bp = W + (size_t)(n0 + r15) * ldb + kq;
  f32x4 acc[NSUB];
  #pragma unroll
  for (int s = 0; s < NSUB; s++) acc[s] = (f32x4){0.f, 0.f, 0.f, 0.f};
  for (int k0 = 0; k0 < K; k0 += 32) {
    bf16x8 a = *(const bf16x8*)(ap + k0);
    #pragma unroll
    for (int s = 0; s < NSUB; s++) {
      bf16x8 b = *(const bf16x8*)(bp + (size_t)s * 16 * ldb + k0);
      acc[s] = __builtin_amdgcn_mfma_f32_16x16x32_bf16(a, b, acc[s], 0, 0, 0);
    }
  }
  int crow = m0 + (lane >> 4) * 4;
  int ccol = n0 + r15;
  #pragma unroll
  for (int s = 0; s < NSUB; s++) {
    #pragma unroll
    for (int r = 0; r < 4; r++)
      C[(size_t)(crow + r) * ldc + ccol + s * 16] = acc[s][r];
  }
}

// ---------------- causal depthwise conv (k=4) + bias + silu ----------------
__global__ __launch_bounds__(256) void k_conv(const float* __restrict__ xz,
                                              const float* __restrict__ cw,
                                              const float* __restrict__ cb,
                                              float* __restrict__ xc,
                                              u16* __restrict__ xcb)
{
  int idx = blockIdx.x * 256 + threadIdx.x;     // over NT_*DI_
  int d = idx & (DI_ - 1);
  int t = idx >> 10;
  int l = t & (L_ - 1);
  const float* base = xz + (size_t)t * (2 * DI_) + d;
  float acc = cb[d] + cw[d * 4 + 3] * base[0];
  if (l >= 1) acc += cw[d * 4 + 2] * base[-(2 * DI_)];
  if (l >= 2) acc += cw[d * 4 + 1] * base[-2 * (2 * DI_)];
  if (l >= 3) acc += cw[d * 4 + 0] * base[-3 * (2 * DI_)];
  float v = acc / (1.f + __expf(-acc));         // silu
  xc[idx]  = v;
  xcb[idx] = f2b(v);
}

// ---------------- dt activation: softplus(dtraw + dt_bias), in-place ----------------
__global__ __launch_bounds__(256) void k_dtact(float* __restrict__ dtr, const float* __restrict__ dtb)
{
  int i = blockIdx.x * 256 + threadIdx.x;       // over NT_*DI_
  float x = dtr[i] + dtb[i & (DI_ - 1)];
  dtr[i] = (x > 20.f) ? x : log1pf(__expf(x));
}

// ---------------- selective scan: thread = (b, d, n); 16-lane reduce over n ----------------
__global__ __launch_bounds__(256) void k_scan(const float* __restrict__ dtf,
                                              const float* __restrict__ xc,
                                              const float* __restrict__ xz,
                                              const float* __restrict__ xdbl,
                                              const float* __restrict__ A_log,
                                              const float* __restrict__ Dp,
                                              u16* __restrict__ yb)
{
  int n  = threadIdx.x & 15;
  int dl = threadIdx.x >> 4;                 // 0..15
  int blk = blockIdx.x;                      // 0..127
  int b = blk >> 6;
  int d = (blk & 63) * 16 + dl;
  float Adn = -__expf(A_log[d * 16 + n]);
  float Dd  = Dp[d];
  float h = 0.f;
  const float* dtp = dtf  + (size_t)b * L_ * DI_ + d;
  const float* xp  = xc   + (size_t)b * L_ * DI_ + d;
  const float* zp  = xz   + (size_t)b * L_ * (2 * DI_) + DI_ + d;
  const float* bcp = xdbl + (size_t)b * L_ * 64;
  u16* yp = yb + (size_t)b * L_ * DI_ + d;
  for (int l = 0; l < L_; l++) {
    float dt = dtp[(size_t)l * DI_];
    float xv = xp[(size_t)l * DI_];
    float Bv = bcp[l * 64 + 32 + n];
    float Cv = bcp[l * 64 + 48 + n];
    float dA = __expf(dt * Adn);
    h = dA * h + dt * xv * Bv;
    float sum = h * Cv;
    sum += __shfl_xor(sum, 1, 16);
    sum += __shfl_xor(sum, 2, 16);
    sum += __shfl_xor(sum, 4, 16);
    sum += __shfl_xor(sum, 8, 16);
    if (n == 0) {
      float zv = zp[(size_t)l * (2 * DI_)];
      float yv = (sum + xv * Dd) * (zv / (1.f + __expf(-zv)));
      yp[(size_t)l * DI_] = f2b(yv);
    }
  }
}

extern "C" void kernel_launch(void* const* d_in, const int* in_sizes, int n_in,
                              void* d_out, int out_size, void* d_ws, size_t ws_size,
                              hipStream_t stream) {
  const float* x         = (const float*)d_in[0];
  const float* norm_w    = (const float*)d_in[1];
  const float* norm_b    = (const float*)d_in[2];
  const float* in_proj_w = (const float*)d_in[3];
  const float* conv_w    = (const float*)d_in[4];
  const float* conv_b    = (const float*)d_in[5];
  const float* x_proj_w  = (const float*)d_in[6];
  const float* dt_proj_w = (const float*)d_in[7];
  const float* dt_proj_b = (const float*)d_in[8];
  const float* A_log     = (const float*)d_in[9];
  const float* Dv        = (const float*)d_in[10];
  const float* out_proj_w= (const float*)d_in[11];
  float* out = (float*)d_out;

  // ---- workspace layout (fp32 region then bf16 region) ----
  float* fb = (float*)d_ws;
  size_t off = 0;
  float* xt   = fb + off; off += (size_t)NT_ * CD_;        // 4 Mi floats (aliased as o_buf later)
  float* xz   = fb + off; off += (size_t)NT_ * 2 * DI_;    // 16 Mi
  float* xc   = fb + off; off += (size_t)NT_ * DI_;        // 8 Mi
  float* dtr  = fb + off; off += (size_t)NT_ * DI_;        // 8 Mi
  float* xdbl = fb + off; off += (size_t)NT_ * 64;         // 0.5 Mi
  u16* ub = (u16*)(fb + off);
  size_t uo = 0;
  u16* xsb   = ub + uo; uo += (size_t)NT_ * CD_;
  u16* xcb   = ub + uo; uo += (size_t)NT_ * DI_;
  u16* xdblb = ub + uo; uo += (size_t)NT_ * 64;
  u16* yb    = ub + uo; uo += (size_t)NT_ * DI_;
  u16* wib   = ub + uo; uo += (size_t)(2 * DI_) * CD_;
  u16* wxb   = ub + uo; uo += (size_t)64 * DI_;
  u16* wdtb  = ub + uo; uo += (size_t)DI_ * 32;
  u16* wob   = ub + uo; uo += (size_t)CD_ * DI_;
  float* o_buf = xt;   // xt is dead after k_ln1; reuse for out_proj output

  dim3 tb(32, 8);
  // 1. x (B,C,L) --clamp+transpose--> xt (B,L,C)
  k_transpose<<<dim3(L_ / 32, CD_ / 32, B_), tb, 0, stream>>>(x, xt, CD_, L_);
  // 2. LN1 -> xs bf16
  k_ln1<<<NT_, 64, 0, stream>>>(xt, norm_w, norm_b, xsb);
  // 3. weight converts
  k_cvt<<<(2 * DI_ * CD_) / 256, 256, 0, stream>>>(in_proj_w, wib, 2 * DI_ * CD_);
  k_cvt<<<(64 * DI_) / 256, 256, 0, stream>>>(x_proj_w, wxb, 64 * DI_);
  k_cvt<<<(DI_ * 32) / 256, 256, 0, stream>>>(dt_proj_w, wdtb, DI_ * 32);
  k_cvt<<<(CD_ * DI_) / 256, 256, 0, stream>>>(out_proj_w, wob, CD_ * DI_);
  // 4. in_proj: xz = xs @ Wi^T   (8192x512 -> 2048)
  k_gemm<8><<<dim3((2 * DI_) / 128, NT_ / 64), 256, 0, stream>>>(xsb, CD_, wib, CD_, xz, 2 * DI_, CD_);
  // 5. causal conv + silu -> xc fp32 + bf16
  k_conv<<<(NT_ * DI_) / 256, 256, 0, stream>>>(xz, conv_w, conv_b, xc, xcb);
  // 6. x_proj: xdbl = xc @ Wx^T  (8192x1024 -> 64)
  k_gemm<4><<<dim3(1, NT_ / 64), 256, 0, stream>>>(xcb, DI_, wxb, DI_, xdbl, 64, DI_);
  // 7. xdbl -> bf16 (for dt GEMM; dt part = first 32 cols, lda=64)
  k_cvt<<<(NT_ * 64) / 256, 256, 0, stream>>>(xdbl, xdblb, NT_ * 64);
  // 8. dt_proj: dtr = xdbl[:, :32] @ Wdt^T  (8192x32 -> 1024)
  k_gemm<8><<<dim3(DI_ / 128, NT_ / 64), 256, 0, stream>>>(xdblb, 64, wdtb, 32, dtr, DI_, 32);
  // 9. softplus(dtr + dt_bias) in place
  k_dtact<<<(NT_ * DI_) / 256, 256, 0, stream>>>(dtr, dt_proj_b);
  // 10. selective scan -> y bf16 (includes +xc*D and *silu(z))
  k_scan<<<128, 256, 0, stream>>>(dtr, xc, xz, xdbl, A_log, Dv, yb);
  // 11. out_proj: o = y @ Wo^T  (8192x1024 -> 512)
  k_gemm<8><<<dim3(CD_ / 128, NT_ / 64), 256, 0, stream>>>(yb, DI_, wob, DI_, o_buf, CD_, DI_);
  // 12. clamp -> LN(1,0) -> clamp, in place
  k_ln2<<<NT_, 64, 0, stream>>>(o_buf);
  // 13. o (B,L,C) -> out (B,C,L)  (clamp idempotent)
  k_transpose<<<dim3(CD_ / 32, L_ / 32, B_), tb, 0, stream>>>(o_buf, out, L_, CD_);
}

// Round 2
// 537.084 us; speedup vs baseline: 6.2768x; 6.2768x over previous
//
#include <hip/hip_runtime.h>
#include <cstdint>
#include <cstddef>

#define B_   2
#define CD_  512      // DIM
#define L_   4096     // H*W
#define DI_  1024     // D_INNER
#define NT_  (B_*L_)  // tokens = 8192
#define NC_  64       // scan chunks
#define LC_  64       // chunk length (NC_*LC_ == L_)

typedef unsigned short u16;
typedef __attribute__((ext_vector_type(8))) short bf16x8;
typedef __attribute__((ext_vector_type(4))) float f32x4;

__device__ __forceinline__ float clampf(float x){ return fminf(10.f, fmaxf(-10.f, x)); }

__device__ __forceinline__ u16 f2b(float f){
  union { float f; unsigned u; } v; v.f = f;
  unsigned u = v.u + 0x7FFFu + ((v.u >> 16) & 1u);   // RNE to bf16
  return (u16)(u >> 16);
}

__device__ __forceinline__ float softplusf(float x){
  return (x > 20.f) ? x : log1pf(__expf(x));
}

// DPP rotate-add within a 16-lane row (VALU pipe, not DS).
// CTRL: row_ror:8=0x128, :4=0x124, :2=0x122, :1=0x121
template<int CTRL>
__device__ __forceinline__ float dpp_add(float x){
  int y = __builtin_amdgcn_update_dpp(0, __float_as_int(x), CTRL, 0xF, 0xF, true);
  return x + __int_as_float(y);
}

// ---------------- transpose + clamp: in (B,R,Cc) -> out (B,Cc,R) ----------------
__global__ __launch_bounds__(256) void k_transpose(const float* __restrict__ in,
                                                   float* __restrict__ out,
                                                   int R, int Cc)
{
  __shared__ float tile[32][33];
  int b = blockIdx.z;
  int c0 = blockIdx.x * 32, r0 = blockIdx.y * 32;
  #pragma unroll
  for (int i = 0; i < 32; i += 8) {
    int r = r0 + threadIdx.y + i, c = c0 + threadIdx.x;
    tile[threadIdx.y + i][threadIdx.x] = in[((size_t)b * R + r) * Cc + c];
  }
  __syncthreads();
  #pragma unroll
  for (int i = 0; i < 32; i += 8) {
    int c = c0 + threadIdx.y + i, r = r0 + threadIdx.x;
    out[((size_t)b * Cc + c) * R + r] = clampf(tile[threadIdx.x][threadIdx.y + i]);
  }
}

// ---------------- LN1: per-token layernorm over 512, writes bf16 ----------------
__global__ __launch_bounds__(64) void k_ln1(const float* __restrict__ xt,
                                            const float* __restrict__ w,
                                            const float* __restrict__ bias,
                                            u16* __restrict__ out)
{
  int t = blockIdx.x, lane = threadIdx.x;
  const float4* row = (const float4*)(xt + (size_t)t * CD_);
  float4 a = row[lane], b = row[lane + 64];
  float s = a.x + a.y + a.z + a.w + b.x + b.y + b.z + b.w;
  float q = a.x*a.x + a.y*a.y + a.z*a.z + a.w*a.w
          + b.x*b.x + b.y*b.y + b.z*b.z + b.w*b.w;
  #pragma unroll
  for (int off = 32; off; off >>= 1) { s += __shfl_xor(s, off, 64); q += __shfl_xor(q, off, 64); }
  float mu = s * (1.f / CD_);
  float rs = rsqrtf(q * (1.f / CD_) - mu * mu + 1e-5f);
  const float4* wv = (const float4*)w;  const float4* bv = (const float4*)bias;
  float4 w0 = wv[lane], w1 = wv[lane + 64], b0 = bv[lane], b1 = bv[lane + 64];
  u16* orow = out + (size_t)t * CD_;
  ushort4 o0, o1;
  o0.x = f2b(clampf((a.x - mu) * rs * w0.x + b0.x));
  o0.y = f2b(clampf((a.y - mu) * rs * w0.y + b0.y));
  o0.z = f2b(clampf((a.z - mu) * rs * w0.z + b0.z));
  o0.w = f2b(clampf((a.w - mu) * rs * w0.w + b0.w));
  o1.x = f2b(clampf((b.x - mu) * rs * w1.x + b1.x));
  o1.y = f2b(clampf((b.y - mu) * rs * w1.y + b1.y));
  o1.z = f2b(clampf((b.z - mu) * rs * w1.z + b1.z));
  o1.w = f2b(clampf((b.w - mu) * rs * w1.w + b1.w));
  ((ushort4*)orow)[lane] = o0;
  ((ushort4*)orow)[lane + 64] = o1;
}

// ---------------- LN2: clamp -> LN(w=1,b=0) -> clamp, fp32 in-place ----------------
__global__ __launch_bounds__(64) void k_ln2(float* __restrict__ o)
{
  int t = blockIdx.x, lane = threadIdx.x;
  float4* row = (float4*)(o + (size_t)t * CD_);
  float4 a = row[lane], b = row[lane + 64];
  a.x = clampf(a.x); a.y = clampf(a.y); a.z = clampf(a.z); a.w = clampf(a.w);
  b.x = clampf(b.x); b.y = clampf(b.y); b.z = clampf(b.z); b.w = clampf(b.w);
  float s = a.x + a.y + a.z + a.w + b.x + b.y + b.z + b.w;
  float q = a.x*a.x + a.y*a.y + a.z*a.z + a.w*a.w
          + b.x*b.x + b.y*b.y + b.z*b.z + b.w*b.w;
  #pragma unroll
  for (int off = 32; off; off >>= 1) { s += __shfl_xor(s, off, 64); q += __shfl_xor(q, off, 64); }
  float mu = s * (1.f / CD_);
  float rs = rsqrtf(q * (1.f / CD_) - mu * mu + 1e-5f);
  float4 r0, r1;
  r0.x = clampf((a.x - mu) * rs); r0.y = clampf((a.y - mu) * rs);
  r0.z = clampf((a.z - mu) * rs); r0.w = clampf((a.w - mu) * rs);
  r1.x = clampf((b.x - mu) * rs); r1.y = clampf((b.y - mu) * rs);
  r1.z = clampf((b.z - mu) * rs); r1.w = clampf((b.w - mu) * rs);
  row[lane] = r0; row[lane + 64] = r1;
}

// ---------------- fp32 -> bf16 convert ----------------
__global__ __launch_bounds__(256) void k_cvt(const float* __restrict__ in, u16* __restrict__ out, int n)
{
  int i = blockIdx.x * 256 + threadIdx.x;
  if (i < n) out[i] = f2b(in[i]);
}

// ---------------- bf16 MFMA GEMM: C[M,N] = A[M,K] * W[N,K]^T ----------------
template<int NSUB>
__global__ __launch_bounds__(256) void k_gemm(const u16* __restrict__ A, int lda,
                                              const u16* __restrict__ W, int ldb,
                                              float* __restrict__ C, int ldc,
                                              int K)
{
  int lane = threadIdx.x & 63;
  int wv   = threadIdx.x >> 6;
  int m0 = blockIdx.y * 64 + wv * 16;
  int n0 = blockIdx.x * (NSUB * 16);
  int r15 = lane & 15;
  int kq  = (lane >> 4) * 8;
  const u16* ap = A + (size_t)(m0 + r15) * lda + kq;
  const u16* bp = W + (size_t)(n0 + r15) * ldb + kq;
  f32x4 acc[NSUB];
  #pragma unroll
  for (int s = 0; s < NSUB; s++) acc[s] = (f32x4){0.f, 0.f, 0.f, 0.f};
  for (int k0 = 0; k0 < K; k0 += 32) {
    bf16x8 a = *(const bf16x8*)(ap + k0);
    #pragma unroll
    for (int s = 0; s < NSUB; s++) {
      bf16x8 b = *(const bf16x8*)(bp + (size_t)s * 16 * ldb + k0);
      acc[s] = __builtin_amdgcn_mfma_f32_16x16x32_bf16(a, b, acc[s], 0, 0, 0);
    }
  }
  int crow = m0 + (lane >> 4) * 4;
  int ccol = n0 + r15;
  #pragma unroll
  for (int s = 0; s < NSUB; s++) {
    #pragma unroll
    for (int r = 0; r < 4; r++)
      C[(size_t)(crow + r) * ldc + ccol + s * 16] = acc[s][r];
  }
}

// ---------------- causal depthwise conv (k=4) + bias + silu ----------------
__global__ __launch_bounds__(256) void k_conv(const float* __restrict__ xz,
                                              const float* __restrict__ cw,
                                              const float* __restrict__ cb,
                                              float* __restrict__ xc,
                                              u16* __restrict__ xcb)
{
  int idx = blockIdx.x * 256 + threadIdx.x;     // over NT_*DI_
  int d = idx & (DI_ - 1);
  int t = idx >> 10;
  int l = t & (L_ - 1);
  const float* base = xz + (size_t)t * (2 * DI_) + d;
  float acc = cb[d] + cw[d * 4 + 3] * base[0];
  if (l >= 1) acc += cw[d * 4 + 2] * base[-(2 * DI_)];
  if (l >= 2) acc += cw[d * 4 + 1] * base[-2 * (2 * DI_)];
  if (l >= 3) acc += cw[d * 4 + 0] * base[-3 * (2 * DI_)];
  float v = acc / (1.f + __expf(-acc));         // silu
  xc[idx]  = v;
  xcb[idx] = f2b(v);
}

// ================= chunk-parallel selective scan =================
// Recurrence per (b,d,n): h <- a*h + u,  a = exp(dt*A_dn), u = dt*x*B_ln.
// Phase 1: per chunk (from h=0): Aprod = prod a, P = partial state.
// Phase 2: serial prefix over chunks: seed_c = H_{c-1}; H_c = Aprod_c*H + P_c.
// Phase 3: re-run chunk from seed, reduce over n (DPP), gate + write y.
// State arrays laid out [b][c][d][n] (= (b*NC_+c)*16384 + d*16 + n).

__global__ __launch_bounds__(256) void k_scan1(const float* __restrict__ dtr,
                                               const float* __restrict__ dtb,
                                               const float* __restrict__ xc,
                                               const float* __restrict__ xdbl,
                                               const float* __restrict__ A_log,
                                               float* __restrict__ Ap_g,
                                               float* __restrict__ Pp_g)
{
  __shared__ float2 dtx_s[LC_ * 16];   // (dt, dt*x) per (l, dl)
  __shared__ float  B_s[LC_ * 16];     // B per (l, n)
  int blk = blockIdx.x;
  int c  = blk & (NC_ - 1);
  int dg = (blk >> 6) & 63;
  int b  = blk >> 12;
  int tid = threadIdx.x;
  int l0 = c * LC_;
  for (int e = tid; e < LC_ * 16; e += 256) {
    int l = e >> 4, i = e & 15;
    int d = dg * 16 + i;
    size_t t = (size_t)(b * L_ + l0 + l);
    float dt = softplusf(dtr[t * DI_ + d] + dtb[d]);
    float xv = xc[t * DI_ + d];
    dtx_s[e] = make_float2(dt, dt * xv);
    B_s[e]   = xdbl[t * 64 + 32 + i];
  }
  __syncthreads();
  int n = tid & 15, dl = tid >> 4;
  float Adn = -__expf(A_log[(dg * 16 + dl) * 16 + n]);
  float Aprod = 1.f, P = 0.f;
  #pragma unroll 8
  for (int l = 0; l < LC_; l++) {
    float2 dx = dtx_s[l * 16 + dl];
    float a = __expf(dx.x * Adn);
    Aprod *= a;
    P = a * P + dx.y * B_s[l * 16 + n];
  }
  size_t idx = (size_t)(b * NC_ + c) * (DI_ * 16) + (dg * 16 + dl) * 16 + n;
  Ap_g[idx] = Aprod;
  Pp_g[idx] = P;
}

__global__ __launch_bounds__(256) void k_scan2(const float* __restrict__ Ap_g,
                                               const float* __restrict__ Pp_g,
                                               float* __restrict__ seed_g)
{
  int blk = blockIdx.x;            // b*64 + dg
  int b = blk >> 6, dg = blk & 63;
  int tid = threadIdx.x;
  float H = 0.f;
  for (int c = 0; c < NC_; c++) {
    size_t idx = (size_t)(b * NC_ + c) * (DI_ * 16) + dg * 256 + tid;
    seed_g[idx] = H;
    H = Ap_g[idx] * H + Pp_g[idx];
  }
}

__global__ __launch_bounds__(256) void k_scan3(const float* __restrict__ dtr,
                                               const float* __restrict__ dtb,
                                               const float* __restrict__ xc,
                                               const float* __restrict__ xz,
                                               const float* __restrict__ xdbl,
                                               const float* __restrict__ A_log,
                                               const float* __restrict__ Dp,
                                               const float* __restrict__ seed_g,
                                               u16* __restrict__ yb)
{
  __shared__ float2 dtx_s[LC_ * 16];   // (dt, dt*x)
  __shared__ float2 BC_s[LC_ * 16];    // (B, C)
  __shared__ float  y_s[LC_ * 16];
  int blk = blockIdx.x;
  int c  = blk & (NC_ - 1);
  int dg = (blk >> 6) & 63;
  int b  = blk >> 12;
  int tid = threadIdx.x;
  int l0 = c * LC_;
  for (int e = tid; e < LC_ * 16; e += 256) {
    int l = e >> 4, i = e & 15;
    int d = dg * 16 + i;
    size_t t = (size_t)(b * L_ + l0 + l);
    float dt = softplusf(dtr[t * DI_ + d] + dtb[d]);
    float xv = xc[t * DI_ + d];
    dtx_s[e] = make_float2(dt, dt * xv);
    BC_s[e]  = make_float2(xdbl[t * 64 + 32 + i], xdbl[t * 64 + 48 + i]);
  }
  __syncthreads();
  int n = tid & 15, dl = tid >> 4;
  float Adn = -__expf(A_log[(dg * 16 + dl) * 16 + n]);
  float h = seed_g[(size_t)(b * NC_ + c) * (DI_ * 16) + (dg * 16 + dl) * 16 + n];
  #pragma unroll 8
  for (int l = 0; l < LC_; l++) {
    float2 dx = dtx_s[l * 16 + dl];
    float a = __expf(dx.x * Adn);
    float2 bc = BC_s[l * 16 + n];
    h = a * h + dx.y * bc.x;
    float s = h * bc.y;
    s = dpp_add<0x128>(s);   // row_ror:8
    s = dpp_add<0x124>(s);   // row_ror:4
    s = dpp_add<0x122>(s);   // row_ror:2
    s = dpp_add<0x121>(s);   // row_ror:1
    if (n == 0) y_s[l * 16 + dl] = s;
  }
  __syncthreads();
  for (int e = tid; e < LC_ * 16; e += 256) {
    int l = e >> 4, i = e & 15;
    int d = dg * 16 + i;
    size_t t = (size_t)(b * L_ + l0 + l);
    float xv = xc[t * DI_ + d];
    float zv = xz[t * (2 * DI_) + DI_ + d];
    float yv = (y_s[e] + xv * Dp[d]) * (zv / (1.f + __expf(-zv)));
    yb[t * DI_ + d] = f2b(yv);
  }
}

extern "C" void kernel_launch(void* const* d_in, const int* in_sizes, int n_in,
                              void* d_out, int out_size, void* d_ws, size_t ws_size,
                              hipStream_t stream) {
  const float* x         = (const float*)d_in[0];
  const float* norm_w    = (const float*)d_in[1];
  const float* norm_b    = (const float*)d_in[2];
  const float* in_proj_w = (const float*)d_in[3];
  const float* conv_w    = (const float*)d_in[4];
  const float* conv_b    = (const float*)d_in[5];
  const float* x_proj_w  = (const float*)d_in[6];
  const float* dt_proj_w = (const float*)d_in[7];
  const float* dt_proj_b = (const float*)d_in[8];
  const float* A_log     = (const float*)d_in[9];
  const float* Dv        = (const float*)d_in[10];
  const float* out_proj_w= (const float*)d_in[11];
  float* out = (float*)d_out;

  // ---- workspace layout (fp32 region then bf16 region) ----
  float* fb = (float*)d_ws;
  size_t off = 0;
  float* xt   = fb + off; off += (size_t)NT_ * CD_;        // reused: seed (scan2/3), o_buf (out_proj)
  float* xz   = fb + off; off += (size_t)NT_ * 2 * DI_;
  float* xc   = fb + off; off += (size_t)NT_ * DI_;
  float* dtr  = fb + off; off += (size_t)NT_ * DI_;
  float* xdbl = fb + off; off += (size_t)NT_ * 64;
  float* Ap   = fb + off; off += (size_t)B_ * NC_ * DI_ * 16;
  float* Pp   = fb + off; off += (size_t)B_ * NC_ * DI_ * 16;
  u16* ub = (u16*)(fb + off);
  size_t uo = 0;
  u16* xsb   = ub + uo; uo += (size_t)NT_ * CD_;
  u16* xcb   = ub + uo; uo += (size_t)NT_ * DI_;
  u16* xdblb = ub + uo; uo += (size_t)NT_ * 64;
  u16* yb    = ub + uo; uo += (size_t)NT_ * DI_;
  u16* wib   = ub + uo; uo += (size_t)(2 * DI_) * CD_;
  u16* wxb   = ub + uo; uo += (size_t)64 * DI_;
  u16* wdtb  = ub + uo; uo += (size_t)DI_ * 32;
  u16* wob   = ub + uo; uo += (size_t)CD_ * DI_;
  float* seed  = xt;   // xt dead after k_ln1; seed dead before out_proj writes o_buf
  float* o_buf = xt;

  dim3 tb(32, 8);
  // 1. x (B,C,L) --clamp+transpose--> xt (B,L,C)
  k_transpose<<<dim3(L_ / 32, CD_ / 32, B_), tb, 0, stream>>>(x, xt, CD_, L_);
  // 2. LN1 -> xs bf16
  k_ln1<<<NT_, 64, 0, stream>>>(xt, norm_w, norm_b, xsb);
  // 3. weight converts
  k_cvt<<<(2 * DI_ * CD_) / 256, 256, 0, stream>>>(in_proj_w, wib, 2 * DI_ * CD_);
  k_cvt<<<(64 * DI_) / 256, 256, 0, stream>>>(x_proj_w, wxb, 64 * DI_);
  k_cvt<<<(DI_ * 32) / 256, 256, 0, stream>>>(dt_proj_w, wdtb, DI_ * 32);
  k_cvt<<<(CD_ * DI_) / 256, 256, 0, stream>>>(out_proj_w, wob, CD_ * DI_);
  // 4. in_proj: xz = xs @ Wi^T   (8192x512 -> 2048)
  k_gemm<8><<<dim3((2 * DI_) / 128, NT_ / 64), 256, 0, stream>>>(xsb, CD_, wib, CD_, xz, 2 * DI_, CD_);
  // 5. causal conv + silu -> xc fp32 + bf16
  k_conv<<<(NT_ * DI_) / 256, 256, 0, stream>>>(xz, conv_w, conv_b, xc, xcb);
  // 6. x_proj: xdbl = xc @ Wx^T  (8192x1024 -> 64)
  k_gemm<4><<<dim3(1, NT_ / 64), 256, 0, stream>>>(xcb, DI_, wxb, DI_, xdbl, 64, DI_);
  // 7. xdbl -> bf16 (dt GEMM reads first 32 cols, lda=64)
  k_cvt<<<(NT_ * 64) / 256, 256, 0, stream>>>(xdbl, xdblb, NT_ * 64);
  // 8. dt_proj: dtr = xdbl[:, :32] @ Wdt^T  (8192x32 -> 1024)  [raw, softplus fused into scan]
  k_gemm<8><<<dim3(DI_ / 128, NT_ / 64), 256, 0, stream>>>(xdblb, 64, wdtb, 32, dtr, DI_, 32);
  // 9. chunk-parallel scan
  k_scan1<<<B_ * 64 * NC_, 256, 0, stream>>>(dtr, dt_proj_b, xc, xdbl, A_log, Ap, Pp);
  k_scan2<<<B_ * 64, 256, 0, stream>>>(Ap, Pp, seed);
  k_scan3<<<B_ * 64 * NC_, 256, 0, stream>>>(dtr, dt_proj_b, xc, xz, xdbl, A_log, Dv, seed, yb);
  // 10. out_proj: o = y @ Wo^T  (8192x1024 -> 512)
  k_gemm<8><<<dim3(CD_ / 128, NT_ / 64), 256, 0, stream>>>(yb, DI_, wob, DI_, o_buf, CD_, DI_);
  // 11. clamp -> LN(1,0) -> clamp, in place
  k_ln2<<<NT_, 64, 0, stream>>>(o_buf);
  // 12. o (B,L,C) -> out (B,C,L)
  k_transpose<<<dim3(CD_ / 32, L_ / 32, B_), tb, 0, stream>>>(o_buf, out, L_, CD_);
}

// Round 3
// 414.425 us; speedup vs baseline: 8.1346x; 1.2960x over previous
//
#include <hip/hip_runtime.h>
#include <cstdint>
#include <cstddef>

#define B_   2
#define CD_  512      // DIM
#define L_   4096     // H*W
#define DI_  1024     // D_INNER
#define NT_  (B_*L_)  // tokens = 8192
#define NC_  64       // scan chunks
#define LC_  64       // chunk length (NC_*LC_ == L_)

typedef unsigned short u16;
typedef __attribute__((ext_vector_type(8))) short bf16x8;
typedef __attribute__((ext_vector_type(4))) float f32x4;

__device__ __forceinline__ float clampf(float x){ return fminf(10.f, fmaxf(-10.f, x)); }

__device__ __forceinline__ u16 f2b(float f){
  union { float f; unsigned u; } v; v.f = f;
  unsigned u = v.u + 0x7FFFu + ((v.u >> 16) & 1u);   // RNE to bf16
  return (u16)(u >> 16);
}

__device__ __forceinline__ float softplusf(float x){
  return (x > 20.f) ? x : log1pf(__expf(x));
}

// async global->LDS, 16 B per lane; LDS dest = wave-uniform base + lane*16
__device__ __forceinline__ void gload_lds16(const u16* g, u16* l){
  __builtin_amdgcn_global_load_lds((const __attribute__((address_space(1))) void*)g,
                                   (__attribute__((address_space(3))) void*)l, 16, 0, 0);
}

// DPP rotate-add within a 16-lane row (VALU pipe, not DS).
template<int CTRL>
__device__ __forceinline__ float dpp_add(float x){
  int y = __builtin_amdgcn_update_dpp(0, __float_as_int(x), CTRL, 0xF, 0xF, true);
  return x + __int_as_float(y);
}

// ---------------- transpose + clamp: in (B,R,Cc) -> out (B,Cc,R) ----------------
__global__ __launch_bounds__(256) void k_transpose(const float* __restrict__ in,
                                                   float* __restrict__ out,
                                                   int R, int Cc)
{
  __shared__ float tile[32][33];
  int b = blockIdx.z;
  int c0 = blockIdx.x * 32, r0 = blockIdx.y * 32;
  #pragma unroll
  for (int i = 0; i < 32; i += 8) {
    int r = r0 + threadIdx.y + i, c = c0 + threadIdx.x;
    tile[threadIdx.y + i][threadIdx.x] = in[((size_t)b * R + r) * Cc + c];
  }
  __syncthreads();
  #pragma unroll
  for (int i = 0; i < 32; i += 8) {
    int c = c0 + threadIdx.y + i, r = r0 + threadIdx.x;
    out[((size_t)b * Cc + c) * R + r] = clampf(tile[threadIdx.x][threadIdx.y + i]);
  }
}

// ---------------- LN1: per-token layernorm over 512, writes bf16 ----------------
__global__ __launch_bounds__(64) void k_ln1(const float* __restrict__ xt,
                                            const float* __restrict__ w,
                                            const float* __restrict__ bias,
                                            u16* __restrict__ out)
{
  int t = blockIdx.x, lane = threadIdx.x;
  const float4* row = (const float4*)(xt + (size_t)t * CD_);
  float4 a = row[lane], b = row[lane + 64];
  float s = a.x + a.y + a.z + a.w + b.x + b.y + b.z + b.w;
  float q = a.x*a.x + a.y*a.y + a.z*a.z + a.w*a.w
          + b.x*b.x + b.y*b.y + b.z*b.z + b.w*b.w;
  #pragma unroll
  for (int off = 32; off; off >>= 1) { s += __shfl_xor(s, off, 64); q += __shfl_xor(q, off, 64); }
  float mu = s * (1.f / CD_);
  float rs = rsqrtf(q * (1.f / CD_) - mu * mu + 1e-5f);
  const float4* wv = (const float4*)w;  const float4* bv = (const float4*)bias;
  float4 w0 = wv[lane], w1 = wv[lane + 64], b0 = bv[lane], b1 = bv[lane + 64];
  u16* orow = out + (size_t)t * CD_;
  ushort4 o0, o1;
  o0.x = f2b(clampf((a.x - mu) * rs * w0.x + b0.x));
  o0.y = f2b(clampf((a.y - mu) * rs * w0.y + b0.y));
  o0.z = f2b(clampf((a.z - mu) * rs * w0.z + b0.z));
  o0.w = f2b(clampf((a.w - mu) * rs * w0.w + b0.w));
  o1.x = f2b(clampf((b.x - mu) * rs * w1.x + b1.x));
  o1.y = f2b(clampf((b.y - mu) * rs * w1.y + b1.y));
  o1.z = f2b(clampf((b.z - mu) * rs * w1.z + b1.z));
  o1.w = f2b(clampf((b.w - mu) * rs * w1.w + b1.w));
  ((ushort4*)orow)[lane] = o0;
  ((ushort4*)orow)[lane + 64] = o1;
}

// ---------------- LN2: clamp -> LN(w=1,b=0) -> clamp, fp32 in-place ----------------
__global__ __launch_bounds__(64) void k_ln2(float* __restrict__ o)
{
  int t = blockIdx.x, lane = threadIdx.x;
  float4* row = (float4*)(o + (size_t)t * CD_);
  float4 a = row[lane], b = row[lane + 64];
  a.x = clampf(a.x); a.y = clampf(a.y); a.z = clampf(a.z); a.w = clampf(a.w);
  b.x = clampf(b.x); b.y = clampf(b.y); b.z = clampf(b.z); b.w = clampf(b.w);
  float s = a.x + a.y + a.z + a.w + b.x + b.y + b.z + b.w;
  float q = a.x*a.x + a.y*a.y + a.z*a.z + a.w*a.w
          + b.x*b.x + b.y*b.y + b.z*b.z + b.w*b.w;
  #pragma unroll
  for (int off = 32; off; off >>= 1) { s += __shfl_xor(s, off, 64); q += __shfl_xor(q, off, 64); }
  float mu = s * (1.f / CD_);
  float rs = rsqrtf(q * (1.f / CD_) - mu * mu + 1e-5f);
  float4 r0, r1;
  r0.x = clampf((a.x - mu) * rs); r0.y = clampf((a.y - mu) * rs);
  r0.z = clampf((a.z - mu) * rs); r0.w = clampf((a.w - mu) * rs);
  r1.x = clampf((b.x - mu) * rs); r1.y = clampf((b.y - mu) * rs);
  r1.z = clampf((b.z - mu) * rs); r1.w = clampf((b.w - mu) * rs);
  row[lane] = r0; row[lane + 64] = r1;
}

// ---------------- fp32 -> bf16 convert ----------------
__global__ __launch_bounds__(256) void k_cvt(const float* __restrict__ in, u16* __restrict__ out, int n)
{
  int i = blockIdx.x * 256 + threadIdx.x;
  if (i < n) out[i] = f2b(in[i]);
}

// ---------------- LDS-tiled bf16 MFMA GEMM (m97 structure) ----------------
// C[M,N] = A[M,K] * W[N,K]^T. 128x128 block tile, BK=32, 4 waves 2x2, each 64x64.
__global__ __launch_bounds__(256) void k_gemm_t(const u16* __restrict__ A,
                                                const u16* __restrict__ W,
                                                float* __restrict__ C,
                                                int K, int N)
{
  __shared__ u16 As[128 * 32];   // 8 KB, row-major [128][32]
  __shared__ u16 Bs[128 * 32];   // 8 KB
  int tid = threadIdx.x;
  int lane = tid & 63, wv = tid >> 6;
  int m0 = blockIdx.y * 128, n0 = blockIdx.x * 128;
  int wm = (wv & 1) * 64, wn = (wv >> 1) * 64;
  int r15 = lane & 15, quad = lane >> 4;

  // staging: chunk ci = wv*2+j covers rows [ci*16, ci*16+16); lane l -> row ci*16+(l>>2), elems (l&3)*8
  int srow = lane >> 2, scol = (lane & 3) * 8;
  const u16* ag0 = A + (size_t)(m0 + (wv*2+0)*16 + srow) * K + scol;
  const u16* ag1 = A + (size_t)(m0 + (wv*2+1)*16 + srow) * K + scol;
  const u16* bg0 = W + (size_t)(n0 + (wv*2+0)*16 + srow) * K + scol;
  const u16* bg1 = W + (size_t)(n0 + (wv*2+1)*16 + srow) * K + scol;
  u16* al0 = As + (wv*2+0) * 512;
  u16* al1 = As + (wv*2+1) * 512;
  u16* bl0 = Bs + (wv*2+0) * 512;
  u16* bl1 = Bs + (wv*2+1) * 512;

  f32x4 acc[4][4];
  #pragma unroll
  for (int i = 0; i < 4; i++)
    #pragma unroll
    for (int j = 0; j < 4; j++) acc[i][j] = (f32x4){0.f, 0.f, 0.f, 0.f};

  for (int k0 = 0; k0 < K; k0 += 32) {
    gload_lds16(ag0 + k0, al0);
    gload_lds16(ag1 + k0, al1);
    gload_lds16(bg0 + k0, bl0);
    gload_lds16(bg1 + k0, bl1);
    __syncthreads();   // drains vmcnt before barrier
    bf16x8 af[4], bfr[4];
    #pragma unroll
    for (int i = 0; i < 4; i++)
      af[i] = *(const bf16x8*)(As + (wm + i*16 + r15) * 32 + quad * 8);
    #pragma unroll
    for (int j = 0; j < 4; j++)
      bfr[j] = *(const bf16x8*)(Bs + (wn + j*16 + r15) * 32 + quad * 8);
    #pragma unroll
    for (int i = 0; i < 4; i++)
      #pragma unroll
      for (int j = 0; j < 4; j++)
        acc[i][j] = __builtin_amdgcn_mfma_f32_16x16x32_bf16(af[i], bfr[j], acc[i][j], 0, 0, 0);
    __syncthreads();
  }
  #pragma unroll
  for (int i = 0; i < 4; i++) {
    int row = m0 + wm + i * 16 + quad * 4;
    #pragma unroll
    for (int j = 0; j < 4; j++) {
      int col = n0 + wn + j * 16 + r15;
      #pragma unroll
      for (int r = 0; r < 4; r++)
        C[(size_t)(row + r) * N + col] = acc[i][j][r];
    }
  }
}

// ---------------- direct GEMM (kept for x_proj, N=64) ----------------
template<int NSUB>
__global__ __launch_bounds__(256) void k_gemm(const u16* __restrict__ A, int lda,
                                              const u16* __restrict__ W, int ldb,
                                              float* __restrict__ C, int ldc,
                                              int K)
{
  int lane = threadIdx.x & 63;
  int wv   = threadIdx.x >> 6;
  int m0 = blockIdx.y * 64 + wv * 16;
  int n0 = blockIdx.x * (NSUB * 16);
  int r15 = lane & 15;
  int kq  = (lane >> 4) * 8;
  const u16* ap = A + (size_t)(m0 + r15) * lda + kq;
  const u16* bp = W + (size_t)(n0 + r15) * ldb + kq;
  f32x4 acc[NSUB];
  #pragma unroll
  for (int s = 0; s < NSUB; s++) acc[s] = (f32x4){0.f, 0.f, 0.f, 0.f};
  for (int k0 = 0; k0 < K; k0 += 32) {
    bf16x8 a = *(const bf16x8*)(ap + k0);
    #pragma unroll
    for (int s = 0; s < NSUB; s++) {
      bf16x8 b = *(const bf16x8*)(bp + (size_t)s * 16 * ldb + k0);
      acc[s] = __builtin_amdgcn_mfma_f32_16x16x32_bf16(a, b, acc[s], 0, 0, 0);
    }
  }
  int crow = m0 + (lane >> 4) * 4;
  int ccol = n0 + r15;
  #pragma unroll
  for (int s = 0; s < NSUB; s++) {
    #pragma unroll
    for (int r = 0; r < 4; r++)
      C[(size_t)(crow + r) * ldc + ccol + s * 16] = acc[s][r];
  }
}

// ---------------- causal depthwise conv (k=4) + bias + silu ----------------
__global__ __launch_bounds__(256) void k_conv(const float* __restrict__ xz,
                                              const float* __restrict__ cw,
                                              const float* __restrict__ cb,
                                              float* __restrict__ xc,
                                              u16* __restrict__ xcb)
{
  int idx = blockIdx.x * 256 + threadIdx.x;     // over NT_*DI_
  int d = idx & (DI_ - 1);
  int t = idx >> 10;
  int l = t & (L_ - 1);
  const float* base = xz + (size_t)t * (2 * DI_) + d;
  float acc = cb[d] + cw[d * 4 + 3] * base[0];
  if (l >= 1) acc += cw[d * 4 + 2] * base[-(2 * DI_)];
  if (l >= 2) acc += cw[d * 4 + 1] * base[-2 * (2 * DI_)];
  if (l >= 3) acc += cw[d * 4 + 0] * base[-3 * (2 * DI_)];
  float v = acc / (1.f + __expf(-acc));         // silu
  xc[idx]  = v;
  xcb[idx] = f2b(v);
}

// ================= chunk-parallel selective scan (dt_proj fused) =================
// dt[t][d] = softplus(dot(xdbl[t][0:32], Wdt[d]) + dtb[d]) computed in-kernel.
// B = xdbl[t][32+n], C = xdbl[t][48+n], both read from the staged xd_s tile.

__global__ __launch_bounds__(256) void k_scan1(const float* __restrict__ xc,
                                               const float* __restrict__ xdbl,
                                               const float* __restrict__ wdt,
                                               const float* __restrict__ dtb,
                                               const float* __restrict__ A_log,
                                               float* __restrict__ Ap_g,
                                               float* __restrict__ Pp_g)
{
  __shared__ float  xd_s[LC_][64];     // 16 KB: xdbl rows for the chunk
  __shared__ float  wdt_s[16][33];     // padded: bank-conflict-free dot
  __shared__ float2 dtx_s[LC_ * 16];   // (dt, dt*x)
  int blk = blockIdx.x;
  int c  = blk & (NC_ - 1);
  int dg = (blk >> 6) & 63;
  int b  = blk >> 12;
  int tid = threadIdx.x;
  int l0 = c * LC_;
  const float4* xd_g = (const float4*)(xdbl + (size_t)(b * L_ + l0) * 64);
  float4* xd_sv = (float4*)&xd_s[0][0];
  for (int e = tid; e < LC_ * 16; e += 256) xd_sv[e] = xd_g[e];
  for (int e = tid; e < 512; e += 256)
    wdt_s[e >> 5][e & 31] = wdt[(dg * 16 + (e >> 5)) * 32 + (e & 31)];
  __syncthreads();
  for (int e = tid; e < LC_ * 16; e += 256) {
    int l = e >> 4, i = e & 15;
    int d = dg * 16 + i;
    float raw = dtb[d];
    #pragma unroll
    for (int r = 0; r < 32; r++) raw += xd_s[l][r] * wdt_s[i][r];
    float dt = softplusf(raw);
    float xv = xc[(size_t)(b * L_ + l0 + l) * DI_ + d];
    dtx_s[e] = make_float2(dt, dt * xv);
  }
  __syncthreads();
  int n = tid & 15, dl = tid >> 4;
  float Adn = -__expf(A_log[(dg * 16 + dl) * 16 + n]);
  float Aprod = 1.f, P = 0.f;
  #pragma unroll 8
  for (int l = 0; l < LC_; l++) {
    float2 dx = dtx_s[l * 16 + dl];
    float a = __expf(dx.x * Adn);
    Aprod *= a;
    P = a * P + dx.y * xd_s[l][32 + n];
  }
  size_t idx = (size_t)(b * NC_ + c) * (DI_ * 16) + (dg * 16 + dl) * 16 + n;
  Ap_g[idx] = Aprod;
  Pp_g[idx] = P;
}

__global__ __launch_bounds__(256) void k_scan2(const float* __restrict__ Ap_g,
                                               const float* __restrict__ Pp_g,
                                               float* __restrict__ seed_g)
{
  int blk = blockIdx.x;            // b*64 + dg
  int b = blk >> 6, dg = blk & 63;
  int tid = threadIdx.x;
  float H = 0.f;
  for (int c = 0; c < NC_; c++) {
    size_t idx = (size_t)(b * NC_ + c) * (DI_ * 16) + dg * 256 + tid;
    seed_g[idx] = H;
    H = Ap_g[idx] * H + Pp_g[idx];
  }
}

__global__ __launch_bounds__(256) void k_scan3(const float* __restrict__ xc,
                                               const float* __restrict__ xz,
                                               const float* __restrict__ xdbl,
                                               const float* __restrict__ wdt,
                                               const float* __restrict__ dtb,
                                               const float* __restrict__ A_log,
                                               const float* __restrict__ Dp,
                                               const float* __restrict__ seed_g,
                                               u16* __restrict__ yb)
{
  __shared__ float  xd_s[LC_][64];
  __shared__ float  wdt_s[16][33];
  __shared__ float2 dtx_s[LC_ * 16];
  __shared__ float  y_s[LC_ * 16];
  int blk = blockIdx.x;
  int c  = blk & (NC_ - 1);
  int dg = (blk >> 6) & 63;
  int b  = blk >> 12;
  int tid = threadIdx.x;
  int l0 = c * LC_;
  const float4* xd_g = (const float4*)(xdbl + (size_t)(b * L_ + l0) * 64);
  float4* xd_sv = (float4*)&xd_s[0][0];
  for (int e = tid; e < LC_ * 16; e += 256) xd_sv[e] = xd_g[e];
  for (int e = tid; e < 512; e += 256)
    wdt_s[e >> 5][e & 31] = wdt[(dg * 16 + (e >> 5)) * 32 + (e & 31)];
  __syncthreads();
  for (int e = tid; e < LC_ * 16; e += 256) {
    int l = e >> 4, i = e & 15;
    int d = dg * 16 + i;
    float raw = dtb[d];
    #pragma unroll
    for (int r = 0; r < 32; r++) raw += xd_s[l][r] * wdt_s[i][r];
    float dt = softplusf(raw);
    float xv = xc[(size_t)(b * L_ + l0 + l) * DI_ + d];
    dtx_s[e] = make_float2(dt, dt * xv);
  }
  __syncthreads();
  int n = tid & 15, dl = tid >> 4;
  float Adn = -__expf(A_log[(dg * 16 + dl) * 16 + n]);
  float h = seed_g[(size_t)(b * NC_ + c) * (DI_ * 16) + (dg * 16 + dl) * 16 + n];
  #pragma unroll 8
  for (int l = 0; l < LC_; l++) {
    float2 dx = dtx_s[l * 16 + dl];
    float a = __expf(dx.x * Adn);
    h = a * h + dx.y * xd_s[l][32 + n];
    float s = h * xd_s[l][48 + n];
    s = dpp_add<0x128>(s);   // row_ror:8
    s = dpp_add<0x124>(s);   // row_ror:4
    s = dpp_add<0x122>(s);   // row_ror:2
    s = dpp_add<0x121>(s);   // row_ror:1
    if (n == 0) y_s[l * 16 + dl] = s;
  }
  __syncthreads();
  for (int e = tid; e < LC_ * 16; e += 256) {
    int l = e >> 4, i = e & 15;
    int d = dg * 16 + i;
    size_t t = (size_t)(b * L_ + l0 + l);
    float xv = xc[t * DI_ + d];
    float zv = xz[t * (2 * DI_) + DI_ + d];
    float yv = (y_s[e] + xv * Dp[d]) * (zv / (1.f + __expf(-zv)));
    yb[t * DI_ + d] = f2b(yv);
  }
}

extern "C" void kernel_launch(void* const* d_in, const int* in_sizes, int n_in,
                              void* d_out, int out_size, void* d_ws, size_t ws_size,
                              hipStream_t stream) {
  const float* x         = (const float*)d_in[0];
  const float* norm_w    = (const float*)d_in[1];
  const float* norm_b    = (const float*)d_in[2];
  const float* in_proj_w = (const float*)d_in[3];
  const float* conv_w    = (const float*)d_in[4];
  const float* conv_b    = (const float*)d_in[5];
  const float* x_proj_w  = (const float*)d_in[6];
  const float* dt_proj_w = (const float*)d_in[7];
  const float* dt_proj_b = (const float*)d_in[8];
  const float* A_log     = (const float*)d_in[9];
  const float* Dv        = (const float*)d_in[10];
  const float* out_proj_w= (const float*)d_in[11];
  float* out = (float*)d_out;

  // ---- workspace layout (fp32 region then bf16 region) ----
  float* fb = (float*)d_ws;
  size_t off = 0;
  float* xt   = fb + off; off += (size_t)NT_ * CD_;        // reused: seed (scan2/3), o_buf (out_proj)
  float* xz   = fb + off; off += (size_t)NT_ * 2 * DI_;
  float* xc   = fb + off; off += (size_t)NT_ * DI_;
  float* xdbl = fb + off; off += (size_t)NT_ * 64;
  float* Ap   = fb + off; off += (size_t)B_ * NC_ * DI_ * 16;
  float* Pp   = fb + off; off += (size_t)B_ * NC_ * DI_ * 16;
  u16* ub = (u16*)(fb + off);
  size_t uo = 0;
  u16* xsb   = ub + uo; uo += (size_t)NT_ * CD_;
  u16* xcb   = ub + uo; uo += (size_t)NT_ * DI_;
  u16* yb    = ub + uo; uo += (size_t)NT_ * DI_;
  u16* wib   = ub + uo; uo += (size_t)(2 * DI_) * CD_;
  u16* wxb   = ub + uo; uo += (size_t)64 * DI_;
  u16* wob   = ub + uo; uo += (size_t)CD_ * DI_;
  float* seed  = xt;   // xt dead after k_ln1; seed dead before out_proj writes o_buf
  float* o_buf = xt;

  dim3 tb(32, 8);
  // 1. x (B,C,L) --clamp+transpose--> xt (B,L,C)
  k_transpose<<<dim3(L_ / 32, CD_ / 32, B_), tb, 0, stream>>>(x, xt, CD_, L_);
  // 2. LN1 -> xs bf16
  k_ln1<<<NT_, 64, 0, stream>>>(xt, norm_w, norm_b, xsb);
  // 3. weight converts
  k_cvt<<<(2 * DI_ * CD_) / 256, 256, 0, stream>>>(in_proj_w, wib, 2 * DI_ * CD_);
  k_cvt<<<(64 * DI_) / 256, 256, 0, stream>>>(x_proj_w, wxb, 64 * DI_);
  k_cvt<<<(CD_ * DI_) / 256, 256, 0, stream>>>(out_proj_w, wob, CD_ * DI_);
  // 4. in_proj: xz = xs @ Wi^T   (8192x512x2048), LDS-tiled
  k_gemm_t<<<dim3((2 * DI_) / 128, NT_ / 128), 256, 0, stream>>>(xsb, wib, xz, CD_, 2 * DI_);
  // 5. causal conv + silu -> xc fp32 + bf16
  k_conv<<<(NT_ * DI_) / 256, 256, 0, stream>>>(xz, conv_w, conv_b, xc, xcb);
  // 6. x_proj: xdbl = xc @ Wx^T  (8192x1024x64), direct
  k_gemm<4><<<dim3(1, NT_ / 64), 256, 0, stream>>>(xcb, DI_, wxb, DI_, xdbl, 64, DI_);
  // 7. chunk-parallel scan (dt_proj + softplus fused inside)
  k_scan1<<<B_ * 64 * NC_, 256, 0, stream>>>(xc, xdbl, dt_proj_w, dt_proj_b, A_log, Ap, Pp);
  k_scan2<<<B_ * 64, 256, 0, stream>>>(Ap, Pp, seed);
  k_scan3<<<B_ * 64 * NC_, 256, 0, stream>>>(xc, xz, xdbl, dt_proj_w, dt_proj_b, A_log, Dv, seed, yb);
  // 8. out_proj: o = y @ Wo^T  (8192x1024x512), LDS-tiled
  k_gemm_t<<<dim3(CD_ / 128, NT_ / 128), 256, 0, stream>>>(yb, wob, o_buf, DI_, CD_);
  // 9. clamp -> LN(1,0) -> clamp, in place
  k_ln2<<<NT_, 64, 0, stream>>>(o_buf);
  // 10. o (B,L,C) -> out (B,C,L)
  k_transpose<<<dim3(CD_ / 32, L_ / 32, B_), tb, 0, stream>>>(o_buf, out, L_, CD_);
}

// Round 4
// 362.152 us; speedup vs baseline: 9.3088x; 1.1443x over previous
//
#include <hip/hip_runtime.h>
#include <cstdint>
#include <cstddef>

#define B_   2
#define CD_  512      // DIM
#define L_   4096     // H*W
#define DI_  1024     // D_INNER
#define NT_  (B_*L_)  // tokens = 8192
#define NC_  64       // scan chunks
#define LC_  64       // chunk length (NC_*LC_ == L_)
#define XDP_ 68       // padded row stride for xd_s (68%32=4 banks/row -> conflict-free col reads)

typedef unsigned short u16;
typedef __attribute__((ext_vector_type(8))) short bf16x8;
typedef __attribute__((ext_vector_type(4))) float f32x4;

__device__ __forceinline__ float clampf(float x){ return fminf(10.f, fmaxf(-10.f, x)); }

__device__ __forceinline__ u16 f2b(float f){
  union { float f; unsigned u; } v; v.f = f;
  unsigned u = v.u + 0x7FFFu + ((v.u >> 16) & 1u);   // RNE to bf16
  return (u16)(u >> 16);
}

// fast softplus: |rel err| ~1e-5, slope at dt~0.01 makes abs err ~1e-7 — negligible
__device__ __forceinline__ float softplusf(float x){
  return (x > 20.f) ? x : __logf(1.f + __expf(x));
}

// async global->LDS, 16 B per lane; LDS dest = wave-uniform base + lane*16
__device__ __forceinline__ void gload_lds16(const u16* g, u16* l){
  __builtin_amdgcn_global_load_lds((const __attribute__((address_space(1))) void*)g,
                                   (__attribute__((address_space(3))) void*)l, 16, 0, 0);
}

// DPP rotate-add within a 16-lane row (VALU pipe, not DS).
template<int CTRL>
__device__ __forceinline__ float dpp_add(float x){
  int y = __builtin_amdgcn_update_dpp(0, __float_as_int(x), CTRL, 0xF, 0xF, true);
  return x + __int_as_float(y);
}

// ---------------- transpose + clamp: in (B,R,Cc) -> out (B,Cc,R) ----------------
__global__ __launch_bounds__(256) void k_transpose(const float* __restrict__ in,
                                                   float* __restrict__ out,
                                                   int R, int Cc)
{
  __shared__ float tile[32][33];
  int b = blockIdx.z;
  int c0 = blockIdx.x * 32, r0 = blockIdx.y * 32;
  #pragma unroll
  for (int i = 0; i < 32; i += 8) {
    int r = r0 + threadIdx.y + i, c = c0 + threadIdx.x;
    tile[threadIdx.y + i][threadIdx.x] = in[((size_t)b * R + r) * Cc + c];
  }
  __syncthreads();
  #pragma unroll
  for (int i = 0; i < 32; i += 8) {
    int c = c0 + threadIdx.y + i, r = r0 + threadIdx.x;
    out[((size_t)b * Cc + c) * R + r] = clampf(tile[threadIdx.x][threadIdx.y + i]);
  }
}

// ---------------- LN1: per-token layernorm over 512, writes bf16 ----------------
__global__ __launch_bounds__(64) void k_ln1(const float* __restrict__ xt,
                                            const float* __restrict__ w,
                                            const float* __restrict__ bias,
                                            u16* __restrict__ out)
{
  int t = blockIdx.x, lane = threadIdx.x;
  const float4* row = (const float4*)(xt + (size_t)t * CD_);
  float4 a = row[lane], b = row[lane + 64];
  float s = a.x + a.y + a.z + a.w + b.x + b.y + b.z + b.w;
  float q = a.x*a.x + a.y*a.y + a.z*a.z + a.w*a.w
          + b.x*b.x + b.y*b.y + b.z*b.z + b.w*b.w;
  #pragma unroll
  for (int off = 32; off; off >>= 1) { s += __shfl_xor(s, off, 64); q += __shfl_xor(q, off, 64); }
  float mu = s * (1.f / CD_);
  float rs = rsqrtf(q * (1.f / CD_) - mu * mu + 1e-5f);
  const float4* wv = (const float4*)w;  const float4* bv = (const float4*)bias;
  float4 w0 = wv[lane], w1 = wv[lane + 64], b0 = bv[lane], b1 = bv[lane + 64];
  u16* orow = out + (size_t)t * CD_;
  ushort4 o0, o1;
  o0.x = f2b(clampf((a.x - mu) * rs * w0.x + b0.x));
  o0.y = f2b(clampf((a.y - mu) * rs * w0.y + b0.y));
  o0.z = f2b(clampf((a.z - mu) * rs * w0.z + b0.z));
  o0.w = f2b(clampf((a.w - mu) * rs * w0.w + b0.w));
  o1.x = f2b(clampf((b.x - mu) * rs * w1.x + b1.x));
  o1.y = f2b(clampf((b.y - mu) * rs * w1.y + b1.y));
  o1.z = f2b(clampf((b.z - mu) * rs * w1.z + b1.z));
  o1.w = f2b(clampf((b.w - mu) * rs * w1.w + b1.w));
  ((ushort4*)orow)[lane] = o0;
  ((ushort4*)orow)[lane + 64] = o1;
}

// ---------------- LN2: clamp -> LN(w=1,b=0) -> clamp, fp32 in-place ----------------
__global__ __launch_bounds__(64) void k_ln2(float* __restrict__ o)
{
  int t = blockIdx.x, lane = threadIdx.x;
  float4* row = (float4*)(o + (size_t)t * CD_);
  float4 a = row[lane], b = row[lane + 64];
  a.x = clampf(a.x); a.y = clampf(a.y); a.z = clampf(a.z); a.w = clampf(a.w);
  b.x = clampf(b.x); b.y = clampf(b.y); b.z = clampf(b.z); b.w = clampf(b.w);
  float s = a.x + a.y + a.z + a.w + b.x + b.y + b.z + b.w;
  float q = a.x*a.x + a.y*a.y + a.z*a.z + a.w*a.w
          + b.x*b.x + b.y*b.y + b.z*b.z + b.w*b.w;
  #pragma unroll
  for (int off = 32; off; off >>= 1) { s += __shfl_xor(s, off, 64); q += __shfl_xor(q, off, 64); }
  float mu = s * (1.f / CD_);
  float rs = rsqrtf(q * (1.f / CD_) - mu * mu + 1e-5f);
  float4 r0, r1;
  r0.x = clampf((a.x - mu) * rs); r0.y = clampf((a.y - mu) * rs);
  r0.z = clampf((a.z - mu) * rs); r0.w = clampf((a.w - mu) * rs);
  r1.x = clampf((b.x - mu) * rs); r1.y = clampf((b.y - mu) * rs);
  r1.z = clampf((b.z - mu) * rs); r1.w = clampf((b.w - mu) * rs);
  row[lane] = r0; row[lane + 64] = r1;
}

// ---------------- fp32 -> bf16 convert ----------------
__global__ __launch_bounds__(256) void k_cvt(const float* __restrict__ in, u16* __restrict__ out, int n)
{
  int i = blockIdx.x * 256 + threadIdx.x;
  if (i < n) out[i] = f2b(in[i]);
}

// ---------------- LDS-tiled bf16 MFMA GEMM (m97 structure) ----------------
// C[M,N] = A[M,K] * W[N,K]^T. 128x128 block tile, BK=32, 4 waves 2x2, each 64x64.
__global__ __launch_bounds__(256) void k_gemm_t(const u16* __restrict__ A,
                                                const u16* __restrict__ W,
                                                float* __restrict__ C,
                                                int K, int N)
{
  __shared__ u16 As[128 * 32];   // 8 KB, row-major [128][32]
  __shared__ u16 Bs[128 * 32];   // 8 KB
  int tid = threadIdx.x;
  int lane = tid & 63, wv = tid >> 6;
  int m0 = blockIdx.y * 128, n0 = blockIdx.x * 128;
  int wm = (wv & 1) * 64, wn = (wv >> 1) * 64;
  int r15 = lane & 15, quad = lane >> 4;

  int srow = lane >> 2, scol = (lane & 3) * 8;
  const u16* ag0 = A + (size_t)(m0 + (wv*2+0)*16 + srow) * K + scol;
  const u16* ag1 = A + (size_t)(m0 + (wv*2+1)*16 + srow) * K + scol;
  const u16* bg0 = W + (size_t)(n0 + (wv*2+0)*16 + srow) * K + scol;
  const u16* bg1 = W + (size_t)(n0 + (wv*2+1)*16 + srow) * K + scol;
  u16* al0 = As + (wv*2+0) * 512;
  u16* al1 = As + (wv*2+1) * 512;
  u16* bl0 = Bs + (wv*2+0) * 512;
  u16* bl1 = Bs + (wv*2+1) * 512;

  f32x4 acc[4][4];
  #pragma unroll
  for (int i = 0; i < 4; i++)
    #pragma unroll
    for (int j = 0; j < 4; j++) acc[i][j] = (f32x4){0.f, 0.f, 0.f, 0.f};

  for (int k0 = 0; k0 < K; k0 += 32) {
    gload_lds16(ag0 + k0, al0);
    gload_lds16(ag1 + k0, al1);
    gload_lds16(bg0 + k0, bl0);
    gload_lds16(bg1 + k0, bl1);
    __syncthreads();
    bf16x8 af[4], bfr[4];
    #pragma unroll
    for (int i = 0; i < 4; i++)
      af[i] = *(const bf16x8*)(As + (wm + i*16 + r15) * 32 + quad * 8);
    #pragma unroll
    for (int j = 0; j < 4; j++)
      bfr[j] = *(const bf16x8*)(Bs + (wn + j*16 + r15) * 32 + quad * 8);
    #pragma unroll
    for (int i = 0; i < 4; i++)
      #pragma unroll
      for (int j = 0; j < 4; j++)
        acc[i][j] = __builtin_amdgcn_mfma_f32_16x16x32_bf16(af[i], bfr[j], acc[i][j], 0, 0, 0);
    __syncthreads();
  }
  #pragma unroll
  for (int i = 0; i < 4; i++) {
    int row = m0 + wm + i * 16 + quad * 4;
    #pragma unroll
    for (int j = 0; j < 4; j++) {
      int col = n0 + wn + j * 16 + r15;
      #pragma unroll
      for (int r = 0; r < 4; r++)
        C[(size_t)(row + r) * N + col] = acc[i][j][r];
    }
  }
}

// ---------------- direct GEMM (kept for x_proj, N=64) ----------------
template<int NSUB>
__global__ __launch_bounds__(256) void k_gemm(const u16* __restrict__ A, int lda,
                                              const u16* __restrict__ W, int ldb,
                                              float* __restrict__ C, int ldc,
                                              int K)
{
  int lane = threadIdx.x & 63;
  int wv   = threadIdx.x >> 6;
  int m0 = blockIdx.y * 64 + wv * 16;
  int n0 = blockIdx.x * (NSUB * 16);
  int r15 = lane & 15;
  int kq  = (lane >> 4) * 8;
  const u16* ap = A + (size_t)(m0 + r15) * lda + kq;
  const u16* bp = W + (size_t)(n0 + r15) * ldb + kq;
  f32x4 acc[NSUB];
  #pragma unroll
  for (int s = 0; s < NSUB; s++) acc[s] = (f32x4){0.f, 0.f, 0.f, 0.f};
  for (int k0 = 0; k0 < K; k0 += 32) {
    bf16x8 a = *(const bf16x8*)(ap + k0);
    #pragma unroll
    for (int s = 0; s < NSUB; s++) {
      bf16x8 b = *(const bf16x8*)(bp + (size_t)s * 16 * ldb + k0);
      acc[s] = __builtin_amdgcn_mfma_f32_16x16x32_bf16(a, b, acc[s], 0, 0, 0);
    }
  }
  int crow = m0 + (lane >> 4) * 4;
  int ccol = n0 + r15;
  #pragma unroll
  for (int s = 0; s < NSUB; s++) {
    #pragma unroll
    for (int r = 0; r < 4; r++)
      C[(size_t)(crow + r) * ldc + ccol + s * 16] = acc[s][r];
  }
}

// ---------------- causal depthwise conv (k=4) + bias + silu ----------------
__global__ __launch_bounds__(256) void k_conv(const float* __restrict__ xz,
                                              const float* __restrict__ cw,
                                              const float* __restrict__ cb,
                                              float* __restrict__ xc,
                                              u16* __restrict__ xcb)
{
  int idx = blockIdx.x * 256 + threadIdx.x;     // over NT_*DI_
  int d = idx & (DI_ - 1);
  int t = idx >> 10;
  int l = t & (L_ - 1);
  const float* base = xz + (size_t)t * (2 * DI_) + d;
  float acc = cb[d] + cw[d * 4 + 3] * base[0];
  if (l >= 1) acc += cw[d * 4 + 2] * base[-(2 * DI_)];
  if (l >= 2) acc += cw[d * 4 + 1] * base[-2 * (2 * DI_)];
  if (l >= 3) acc += cw[d * 4 + 0] * base[-3 * (2 * DI_)];
  float v = acc / (1.f + __expf(-acc));         // silu
  xc[idx]  = v;
  xcb[idx] = f2b(v);
}

// ================= chunk-parallel selective scan (dt_proj via MFMA) =================
// dt tile per block = 64 tokens x 16 d, K=32  ->  one mfma_f32_16x16x32_bf16 per wave.
// A-frag = xd_s[token][quad*8+j] (cvt f32->bf16), B-frag = wdt_s[d][quad*8+j].
// D layout: token-in-tile = quad*4+r, d-in-group = lane&15.

__device__ __forceinline__ void dt_mfma_stage(const float (*xd_s)[XDP_],
                                              const float (*wdt_s)[36],
                                              const float* __restrict__ dtb,
                                              const float* __restrict__ xc,
                                              int b, int l0, int dg,
                                              int lane, int wv,
                                              float2* dtx_s)
{
  int r15 = lane & 15, quad = lane >> 4;
  int tok = wv * 16 + r15;
  bf16x8 af, bfv;
  #pragma unroll
  for (int j = 0; j < 8; j++) af[j] = (short)f2b(xd_s[tok][quad * 8 + j]);
  #pragma unroll
  for (int j = 0; j < 8; j++) bfv[j] = (short)f2b(wdt_s[r15][quad * 8 + j]);
  f32x4 dta = (f32x4){0.f, 0.f, 0.f, 0.f};
  dta = __builtin_amdgcn_mfma_f32_16x16x32_bf16(af, bfv, dta, 0, 0, 0);
  int d = dg * 16 + r15;
  float db = dtb[d];
  #pragma unroll
  for (int r = 0; r < 4; r++) {
    int tk = wv * 16 + quad * 4 + r;
    float dt = softplusf(dta[r] + db);
    float xv = xc[(size_t)(b * L_ + l0 + tk) * DI_ + d];
    dtx_s[tk * 16 + r15] = make_float2(dt, dt * xv);
  }
}

__global__ __launch_bounds__(256) void k_scan1(const float* __restrict__ xc,
                                               const float* __restrict__ xdbl,
                                               const float* __restrict__ wdt,
                                               const float* __restrict__ dtb,
                                               const float* __restrict__ A_log,
                                               float* __restrict__ Ap_g,
                                               float* __restrict__ Pp_g)
{
  __shared__ float  xd_s[LC_][XDP_];   // padded: col reads are 2-way (free)
  __shared__ float  wdt_s[16][36];
  __shared__ float2 dtx_s[LC_ * 16];
  int blk = blockIdx.x;
  int c  = blk & (NC_ - 1);
  int dg = (blk >> 6) & 63;
  int b  = blk >> 12;
  int tid = threadIdx.x;
  int lane = tid & 63, wv = tid >> 6;
  int l0 = c * LC_;
  const float4* xd_g = (const float4*)(xdbl + (size_t)(b * L_ + l0) * 64);
  for (int e = tid; e < LC_ * 16; e += 256)
    ((float4*)&xd_s[e >> 4][0])[e & 15] = xd_g[e];
  for (int e = tid; e < 512; e += 256)
    wdt_s[e >> 5][e & 31] = wdt[dg * 512 + e];
  __syncthreads();
  dt_mfma_stage(xd_s, wdt_s, dtb, xc, b, l0, dg, lane, wv, dtx_s);
  __syncthreads();
  int n = tid & 15, dl = tid >> 4;
  float Adn = -__expf(A_log[(dg * 16 + dl) * 16 + n]);
  float Aprod = 1.f, P = 0.f;
  #pragma unroll 8
  for (int l = 0; l < LC_; l++) {
    float2 dx = dtx_s[l * 16 + dl];
    float a = __expf(dx.x * Adn);
    Aprod *= a;
    P = a * P + dx.y * xd_s[l][32 + n];
  }
  size_t idx = (size_t)(b * NC_ + c) * (DI_ * 16) + (dg * 16 + dl) * 16 + n;
  Ap_g[idx] = Aprod;
  Pp_g[idx] = P;
}

__global__ __launch_bounds__(256) void k_scan2(const float* __restrict__ Ap_g,
                                               const float* __restrict__ Pp_g,
                                               float* __restrict__ seed_g)
{
  int blk = blockIdx.x;            // b*64 + dg
  int b = blk >> 6, dg = blk & 63;
  int tid = threadIdx.x;
  float H = 0.f;
  for (int c = 0; c < NC_; c++) {
    size_t idx = (size_t)(b * NC_ + c) * (DI_ * 16) + dg * 256 + tid;
    seed_g[idx] = H;
    H = Ap_g[idx] * H + Pp_g[idx];
  }
}

__global__ __launch_bounds__(256) void k_scan3(const float* __restrict__ xc,
                                               const float* __restrict__ xz,
                                               const float* __restrict__ xdbl,
                                               const float* __restrict__ wdt,
                                               const float* __restrict__ dtb,
                                               const float* __restrict__ A_log,
                                               const float* __restrict__ Dp,
                                               const float* __restrict__ seed_g,
                                               u16* __restrict__ yb)
{
  __shared__ float  xd_s[LC_][XDP_];
  __shared__ float  wdt_s[16][36];
  __shared__ float2 dtx_s[LC_ * 16];
  __shared__ float  y_s[LC_ * 16];
  int blk = blockIdx.x;
  int c  = blk & (NC_ - 1);
  int dg = (blk >> 6) & 63;
  int b  = blk >> 12;
  int tid = threadIdx.x;
  int lane = tid & 63, wv = tid >> 6;
  int l0 = c * LC_;
  const float4* xd_g = (const float4*)(xdbl + (size_t)(b * L_ + l0) * 64);
  for (int e = tid; e < LC_ * 16; e += 256)
    ((float4*)&xd_s[e >> 4][0])[e & 15] = xd_g[e];
  for (int e = tid; e < 512; e += 256)
    wdt_s[e >> 5][e & 31] = wdt[dg * 512 + e];
  __syncthreads();
  dt_mfma_stage(xd_s, wdt_s, dtb, xc, b, l0, dg, lane, wv, dtx_s);
  __syncthreads();
  int n = tid & 15, dl = tid >> 4;
  float Adn = -__expf(A_log[(dg * 16 + dl) * 16 + n]);
  float h = seed_g[(size_t)(b * NC_ + c) * (DI_ * 16) + (dg * 16 + dl) * 16 + n];
  #pragma unroll 8
  for (int l = 0; l < LC_; l++) {
    float2 dx = dtx_s[l * 16 + dl];
    float a = __expf(dx.x * Adn);
    h = a * h + dx.y * xd_s[l][32 + n];
    float s = h * xd_s[l][48 + n];
    s = dpp_add<0x128>(s);   // row_ror:8
    s = dpp_add<0x124>(s);   // row_ror:4
    s = dpp_add<0x122>(s);   // row_ror:2
    s = dpp_add<0x121>(s);   // row_ror:1
    if (n == 0) y_s[l * 16 + dl] = s;
  }
  __syncthreads();
  for (int e = tid; e < LC_ * 16; e += 256) {
    int l = e >> 4, i = e & 15;
    int d = dg * 16 + i;
    size_t t = (size_t)(b * L_ + l0 + l);
    float xv = xc[t * DI_ + d];
    float zv = xz[t * (2 * DI_) + DI_ + d];
    float yv = (y_s[e] + xv * Dp[d]) * (zv / (1.f + __expf(-zv)));
    yb[t * DI_ + d] = f2b(yv);
  }
}

extern "C" void kernel_launch(void* const* d_in, const int* in_sizes, int n_in,
                              void* d_out, int out_size, void* d_ws, size_t ws_size,
                              hipStream_t stream) {
  const float* x         = (const float*)d_in[0];
  const float* norm_w    = (const float*)d_in[1];
  const float* norm_b    = (const float*)d_in[2];
  const float* in_proj_w = (const float*)d_in[3];
  const float* conv_w    = (const float*)d_in[4];
  const float* conv_b    = (const float*)d_in[5];
  const float* x_proj_w  = (const float*)d_in[6];
  const float* dt_proj_w = (const float*)d_in[7];
  const float* dt_proj_b = (const float*)d_in[8];
  const float* A_log     = (const float*)d_in[9];
  const float* Dv        = (const float*)d_in[10];
  const float* out_proj_w= (const float*)d_in[11];
  float* out = (float*)d_out;

  // ---- workspace layout (fp32 region then bf16 region) ----
  float* fb = (float*)d_ws;
  size_t off = 0;
  float* xt   = fb + off; off += (size_t)NT_ * CD_;        // reused: seed (scan2/3), o_buf (out_proj)
  float* xz   = fb + off; off += (size_t)NT_ * 2 * DI_;
  float* xc   = fb + off; off += (size_t)NT_ * DI_;
  float* xdbl = fb + off; off += (size_t)NT_ * 64;
  float* Ap   = fb + off; off += (size_t)B_ * NC_ * DI_ * 16;
  float* Pp   = fb + off; off += (size_t)B_ * NC_ * DI_ * 16;
  u16* ub = (u16*)(fb + off);
  size_t uo = 0;
  u16* xsb   = ub + uo; uo += (size_t)NT_ * CD_;
  u16* xcb   = ub + uo; uo += (size_t)NT_ * DI_;
  u16* yb    = ub + uo; uo += (size_t)NT_ * DI_;
  u16* wib   = ub + uo; uo += (size_t)(2 * DI_) * CD_;
  u16* wxb   = ub + uo; uo += (size_t)64 * DI_;
  u16* wob   = ub + uo; uo += (size_t)CD_ * DI_;
  float* seed  = xt;   // xt dead after k_ln1; seed dead before out_proj writes o_buf
  float* o_buf = xt;

  dim3 tb(32, 8);
  // 1. x (B,C,L) --clamp+transpose--> xt (B,L,C)
  k_transpose<<<dim3(L_ / 32, CD_ / 32, B_), tb, 0, stream>>>(x, xt, CD_, L_);
  // 2. LN1 -> xs bf16
  k_ln1<<<NT_, 64, 0, stream>>>(xt, norm_w, norm_b, xsb);
  // 3. weight converts
  k_cvt<<<(2 * DI_ * CD_) / 256, 256, 0, stream>>>(in_proj_w, wib, 2 * DI_ * CD_);
  k_cvt<<<(64 * DI_) / 256, 256, 0, stream>>>(x_proj_w, wxb, 64 * DI_);
  k_cvt<<<(CD_ * DI_) / 256, 256, 0, stream>>>(out_proj_w, wob, CD_ * DI_);
  // 4. in_proj: xz = xs @ Wi^T   (8192x512x2048), LDS-tiled
  k_gemm_t<<<dim3((2 * DI_) / 128, NT_ / 128), 256, 0, stream>>>(xsb, wib, xz, CD_, 2 * DI_);
  // 5. causal conv + silu -> xc fp32 + bf16
  k_conv<<<(NT_ * DI_) / 256, 256, 0, stream>>>(xz, conv_w, conv_b, xc, xcb);
  // 6. x_proj: xdbl = xc @ Wx^T  (8192x1024x64), direct
  k_gemm<4><<<dim3(1, NT_ / 64), 256, 0, stream>>>(xcb, DI_, wxb, DI_, xdbl, 64, DI_);
  // 7. chunk-parallel scan (dt_proj via in-kernel MFMA)
  k_scan1<<<B_ * 64 * NC_, 256, 0, stream>>>(xc, xdbl, dt_proj_w, dt_proj_b, A_log, Ap, Pp);
  k_scan2<<<B_ * 64, 256, 0, stream>>>(Ap, Pp, seed);
  k_scan3<<<B_ * 64 * NC_, 256, 0, stream>>>(xc, xz, xdbl, dt_proj_w, dt_proj_b, A_log, Dv, seed, yb);
  // 8. out_proj: o = y @ Wo^T  (8192x1024x512), LDS-tiled
  k_gemm_t<<<dim3(CD_ / 128, NT_ / 128), 256, 0, stream>>>(yb, wob, o_buf, DI_, CD_);
  // 9. clamp -> LN(1,0) -> clamp, in place
  k_ln2<<<NT_, 64, 0, stream>>>(o_buf);
  // 10. o (B,L,C) -> out (B,C,L)
  k_transpose<<<dim3(CD_ / 32, L_ / 32, B_), tb, 0, stream>>>(o_buf, out, L_, CD_);
}